// Round 2
// baseline (234.782 us; speedup 1.0000x reference)
//
#include <hip/hip_runtime.h>

// Fast Walsh-Hadamard Transform, N=4096 per row, fp32, BATCH=8192.
// H_4096 = H_16(bits 0-3) ⊗ H_16(bits 4-7) ⊗ H_16(bits 8-11).
// One block (256 threads) per row; 16 elements/thread in registers;
// 3 LDS transposes (the last one purely to vectorize the store).

#define N 4096
#define LDS_STRIDE 17   // pad 16->17 floats/row: scalar ds ops land <=3-way (free-ish)

__device__ __forceinline__ void h16(float r[16]) {
    #pragma unroll
    for (int s = 1; s < 16; s <<= 1) {
        #pragma unroll
        for (int m = 0; m < 16; ++m) {
            if (!(m & s)) {
                float x = r[m], y = r[m ^ s];
                r[m]     = x + y;
                r[m ^ s] = x - y;
            }
        }
    }
}

__global__ __launch_bounds__(256) void fwht4096_kernel(const float* __restrict__ in,
                                                       float* __restrict__ out) {
    __shared__ float lds[256 * LDS_STRIDE];  // 17408 B -> 8 blocks/CU (wave-capped)

    const int t = threadIdx.x;
    const long long row = blockIdx.x;
    const float* __restrict__ rowIn  = in  + row * (long long)N;
    float* __restrict__       rowOut = out + row * (long long)N;

    float r[16];

    // ---- Load: thread t owns e = t*16 + a (a=0..15). 4x dwordx4, coalesced. ----
    #pragma unroll
    for (int q = 0; q < 4; ++q) {
        const float4 v = *reinterpret_cast<const float4*>(rowIn + t * 16 + q * 4);
        r[q * 4 + 0] = v.x; r[q * 4 + 1] = v.y;
        r[q * 4 + 2] = v.z; r[q * 4 + 3] = v.w;
    }

    // ---- Phase A: H16 on element bits 0-3 (strides 1,2,4,8) ----
    h16(r);

    // LDS address of element e: 17*(e>>4) + (e&15)
    // ---- Transpose 1: to register-index = bits 4-7 ----
    #pragma unroll
    for (int i = 0; i < 16; ++i) lds[LDS_STRIDE * t + i] = r[i];    // banks: 2-way, free
    __syncthreads();

    const int a = t & 15;
    const int c = t >> 4;
    #pragma unroll
    for (int k = 0; k < 16; ++k)                    // e = c*256 + k*16 + a
        r[k] = lds[LDS_STRIDE * (c * 16 + k) + a];  // banks: 2-way, free

    // ---- Phase B: H16 on element bits 4-7 (strides 16..128) ----
    h16(r);

    __syncthreads();
    #pragma unroll
    for (int k = 0; k < 16; ++k)
        lds[LDS_STRIDE * (c * 16 + k) + a] = r[k];
    __syncthreads();

    // ---- Transpose 2: to register-index = bits 8-11 ----
    const int b = t >> 4;
    #pragma unroll
    for (int k = 0; k < 16; ++k)                    // e = k*256 + b*16 + a
        r[k] = lds[LDS_STRIDE * (k * 16 + b) + a];  // banks: <=3-way

    // ---- Phase C: H16 on element bits 8-11 (strides 256..2048) ----
    h16(r);

    // ---- Transpose 3: back to contiguous ownership for vectorized store ----
    __syncthreads();
    #pragma unroll
    for (int k = 0; k < 16; ++k)
        lds[LDS_STRIDE * (k * 16 + b) + a] = r[k];  // banks: <=3-way
    __syncthreads();

    #pragma unroll
    for (int i = 0; i < 16; ++i)                    // e = t*16 + i
        r[i] = lds[LDS_STRIDE * t + i];             // banks: 2-way, free

    // ---- Store: 4x dwordx4, contiguous per thread, fully coalesced ----
    #pragma unroll
    for (int q = 0; q < 4; ++q) {
        float4 v;
        v.x = r[q * 4 + 0]; v.y = r[q * 4 + 1];
        v.z = r[q * 4 + 2]; v.w = r[q * 4 + 3];
        *reinterpret_cast<float4*>(rowOut + t * 16 + q * 4) = v;
    }
}

extern "C" void kernel_launch(void* const* d_in, const int* in_sizes, int n_in,
                              void* d_out, int out_size, void* d_ws, size_t ws_size,
                              hipStream_t stream) {
    const float* x = (const float*)d_in[0];
    float* y = (float*)d_out;
    const int rows = in_sizes[0] / N;   // 8192
    fwht4096_kernel<<<rows, 256, 0, stream>>>(x, y);
}

// Round 3
// 228.235 us; speedup vs baseline: 1.0287x; 1.0287x over previous
//
#include <hip/hip_runtime.h>

// FWHT N=4096/row fp32, BATCH=8192. H4096 = H16(b0-3) ⊗ H16(b4-7) ⊗ H16(b8-11),
// phases reordered (commute) so the contiguous-ownership phase is first (fused
// with the global load) and the last phase stores directly (no write-back).
//
// LDS layout: element e lives at word A(e) = e ^ (((e>>8)&1)<<4) ^ (((e>>5)&3)<<2).
// Involution; keeps 16B chunks contiguous (only flips word bits 2-4), so:
//  - phase-A write: 4x ds_write_b128, ~2-way banks
//  - phase-B/C scalar reads/writes: exactly 2-way banks (free, m136)
// DS ops/thread: 4xb128 + 48xb32  (was 96xb32). Barriers: 2 (was 5).

#define N 4096

__device__ __forceinline__ void h16(float r[16]) {
    #pragma unroll
    for (int s = 1; s < 16; s <<= 1) {
        #pragma unroll
        for (int m = 0; m < 16; ++m) {
            if (!(m & s)) {
                float x = r[m], y = r[m ^ s];
                r[m]     = x + y;
                r[m ^ s] = x - y;
            }
        }
    }
}

__global__ __launch_bounds__(256, 8) void fwht4096_kernel(const float* __restrict__ in,
                                                          float* __restrict__ out) {
    __shared__ float lds[N];  // 16384 B, linear+swizzled -> 8 blocks/CU (wave-capped)

    const int t = threadIdx.x;
    const long long row = blockIdx.x;
    const float* __restrict__ rowIn  = in  + row * (long long)N;
    float* __restrict__       rowOut = out + row * (long long)N;

    float r[16];

    // ---- Load: thread t owns e = 16t+i, 4x dwordx4 coalesced ----
    #pragma unroll
    for (int j = 0; j < 4; ++j) {
        const float4 v = *reinterpret_cast<const float4*>(rowIn + t * 16 + j * 4);
        r[j * 4 + 0] = v.x; r[j * 4 + 1] = v.y;
        r[j * 4 + 2] = v.z; r[j * 4 + 3] = v.w;
    }

    // ---- Phase A: H16 on element bits 0-3 (strides 1..8) ----
    h16(r);

    // ---- Write to swizzled layout: word base 16*(t^x), chunk c holds i=4*(c^s).. ----
    const int x = (t >> 4) & 1;   // (e>>8)&1 for e=16t+i
    const int s = (t >> 1) & 3;   // (e>>5)&3 for e=16t+i
    float* wbase = &lds[16 * (t ^ x)];
    #pragma unroll
    for (int c = 0; c < 4; ++c) {
        const int i0 = 4 * (c ^ s);
        const float4 v = make_float4(r[i0], r[i0 + 1], r[i0 + 2], r[i0 + 3]);
        *reinterpret_cast<float4*>(wbase + 4 * c) = v;   // ds_write_b128, 16B aligned
    }
    __syncthreads();

    // ---- Phase B: H16 on element bits 4-7. e = 256*chi + 16k + a ----
    {
        const int chi = t >> 4, a = t & 15;
        const int base = 256 * chi + a;
        const int fx = (chi & 1) << 4;
        #pragma unroll
        for (int k = 0; k < 16; ++k)
            r[k] = lds[(base + 16 * k) ^ fx ^ (((k >> 1) & 3) << 2)];
        h16(r);
        #pragma unroll
        for (int k = 0; k < 16; ++k)   // write back to the very addresses we read
            lds[(base + 16 * k) ^ fx ^ (((k >> 1) & 3) << 2)] = r[k];
    }
    __syncthreads();

    // ---- Phase C: H16 on element bits 8-11. e = 256k + 16b + a = 256k + t ----
    {
        const int b = t >> 4, a = t & 15;
        const int base = 16 * b + a;          // == t
        const int fb = ((b >> 1) & 3) << 2;
        #pragma unroll
        for (int k = 0; k < 16; ++k)
            r[k] = lds[(256 * k + base) ^ ((k & 1) << 4) ^ fb];
        h16(r);
        // ---- Store directly: e = 256k + t -> 256B-contiguous dword stores ----
        #pragma unroll
        for (int k = 0; k < 16; ++k)
            rowOut[k * 256 + t] = r[k];
    }
}

extern "C" void kernel_launch(void* const* d_in, const int* in_sizes, int n_in,
                              void* d_out, int out_size, void* d_ws, size_t ws_size,
                              hipStream_t stream) {
    const float* x = (const float*)d_in[0];
    float* y = (float*)d_out;
    const int rows = in_sizes[0] / N;   // 8192
    fwht4096_kernel<<<rows, 256, 0, stream>>>(x, y);
}